// Round 12
// baseline (223.169 us; speedup 1.0000x reference)
//
#include <hip/hip_runtime.h>
#include <hip/hip_fp16.h>

#define DM   1024
#define NH   16
#define HD   64
#define BATCH 4
#define SEQ  2048
#define MROWS (BATCH*SEQ)            // 8192
#define BHSD  ((size_t)BATCH*NH*SEQ*HD)  // 8388608 elems

using f32x4 = __attribute__((ext_vector_type(4))) float;
using f16x8 = __attribute__((ext_vector_type(8))) _Float16;
using f16x4 = __attribute__((ext_vector_type(4))) _Float16;
using fp16x2 = __attribute__((ext_vector_type(2))) __fp16;
using u32x2 = __attribute__((ext_vector_type(2))) unsigned int;

__device__ __forceinline__ void gload_lds16(const void* g, void* l) {
    __builtin_amdgcn_global_load_lds(
        (const __attribute__((address_space(1))) void*)g,
        (__attribute__((address_space(3))) void*)l, 16, 0, 0);
}

// ---- VALU-pipe cross-lane reduces via permlane*_swap builtins ----
__device__ __forceinline__ float red16_max(float v) {
    u32x2 r = __builtin_amdgcn_permlane16_swap(__float_as_uint(v), __float_as_uint(v), false, false);
    return fmaxf(__uint_as_float(r[0]), __uint_as_float(r[1]));
}
__device__ __forceinline__ float red32_max(float v) {
    u32x2 r = __builtin_amdgcn_permlane32_swap(__float_as_uint(v), __float_as_uint(v), false, false);
    return fmaxf(__uint_as_float(r[0]), __uint_as_float(r[1]));
}
__device__ __forceinline__ float red16_add(float v) {
    u32x2 r = __builtin_amdgcn_permlane16_swap(__float_as_uint(v), __float_as_uint(v), false, false);
    return __uint_as_float(r[0]) + __uint_as_float(r[1]);
}
__device__ __forceinline__ float red32_add(float v) {
    u32x2 r = __builtin_amdgcn_permlane32_swap(__float_as_uint(v), __float_as_uint(v), false, false);
    return __uint_as_float(r[0]) + __uint_as_float(r[1]);
}

// ---------------- fp32 -> fp16 cast ----------------
__global__ __launch_bounds__(256) void f32_to_f16(const float* __restrict__ in,
                                                  _Float16* __restrict__ out, int n) {
    int i = (blockIdx.x * 256 + threadIdx.x) * 4;
    if (i >= n) return;
    float4 v = *(const float4*)(in + i);
    union { _Float16 h[4]; ushort4 u; } cv;
    cv.h[0] = (_Float16)v.x; cv.h[1] = (_Float16)v.y;
    cv.h[2] = (_Float16)v.z; cv.h[3] = (_Float16)v.w;
    *(ushort4*)(out + i) = cv.u;
}

// ---------------- RoPE cos/sin table: [SEQ][32] float2 ----------------
__global__ __launch_bounds__(256) void rope_table(const int* __restrict__ pos,
                                                  float2* __restrict__ tab) {
    int idx = blockIdx.x * 256 + threadIdx.x;    // 65536
    int s = idx >> 5, j = idx & 31;
    float p = (float)pos[s];
    float invf = powf(10000.0f, -(float)j / 32.0f);
    float ang = p * invf;
    tab[idx] = make_float2(cosf(ang), sinf(ang));
}

// ---------------- GEMM, continuous-pipeline (R11 race FIXED): C = A(MxK) * W^T ---------
// 3-buffer rotation; per K-tile:
//   reads buf[t] -> lgkmcnt(0) -> barrier1 (all waves done reading)
//   -> STAGE(t+3 into buf[t%3]) -> MFMA -> counted vmcnt (drain t+1 ONLY)
//   -> barrier2 (all waves' t+1 loads landed -> next reads safe)
// Every LDS read is protected by (own-wait -> barrier); t+2/t+3 loads stay in
// flight across barriers -> continuous staging stream, no vmcnt(0) drain.
// MODE 1 (QKV): BM=256 BN=256, 8 waves 2Mx4N (wave-tile 128x64), L=4 loads/stage.
// MODE 0 (WO):  BM=256 BN=128, 8 waves 4Mx2N (wave-tile 64x64),  L=3 loads/stage.
template<int MODE>
__global__ __launch_bounds__(512, 1)
void gemmP(const _Float16* __restrict__ A, const _Float16* __restrict__ Bw,
           float* __restrict__ outF, _Float16* __restrict__ qkv,
           const float2* __restrict__ rope) {
    constexpr int NK = DM / 32;                    // 32 K-tiles of BK=32
    constexpr int BN = MODE ? 256 : 128;
    constexpr int WTM = MODE ? 8 : 4;              // acc rows (x16)
    constexpr int BL = MODE ? 2 : 1;               // B-tile loads per thread
    __shared__ __align__(16) _Float16 ldsA[3][256][32];   // 48 KB
    __shared__ __align__(16) _Float16 ldsB[3][BN][32];    // 48/24 KB

    const int tid  = threadIdx.x;
    const int lane = tid & 63;
    const int wid  = tid >> 6;                     // 0..7

    // XCD-aware block swizzle (grid.x*grid.y is a multiple of 8)
    const int nwg  = gridDim.x * gridDim.y;
    const int flat = blockIdx.y * gridDim.x + blockIdx.x;
    const int swz  = (flat % 8) * (nwg >> 3) + (flat >> 3);
    const int m0 = (swz % gridDim.x) * 256;
    const int n0 = (swz / gridDim.x) * BN;

    const int wm = MODE ? ((wid >> 2) * 128) : ((wid >> 1) * 64);
    const int wn = MODE ? ((wid & 3) * 64)   : ((wid & 1) * 64);
    const int g   = lane >> 4;
    const int r16 = lane & 15;

    // staging: unit u -> row = u>>2, phys chunk u&3 holds logical chunk
    // (u&3)^((row>>1)&3); source pre-swizzled, LDS dest linear (R8-proven).
    const _Float16* srcA[2];
    int dstA[2];
    #pragma unroll
    for (int L = 0; L < 2; ++L) {
        const int u = L*512 + tid, row = u >> 2, c = (u & 3) ^ ((row >> 1) & 3);
        srcA[L] = A + (size_t)(m0 + row)*DM + c*8;
        dstA[L] = u*8;
    }
    const _Float16* srcB[BL];
    int dstB[BL];
    #pragma unroll
    for (int L = 0; L < BL; ++L) {
        const int u = L*512 + tid, row = u >> 2, c = (u & 3) ^ ((row >> 1) & 3);
        srcB[L] = Bw + (size_t)(n0 + row)*DM + c*8;
        dstB[L] = u*8;
    }

    #define STAGE(buf, kt) do {                                        \
        const int ko = (kt)*32;                                        \
        _Float16* bA = &ldsA[(buf)][0][0];                             \
        _Float16* bB = &ldsB[(buf)][0][0];                             \
        gload_lds16(srcA[0] + ko, bA + dstA[0]);                       \
        gload_lds16(srcA[1] + ko, bA + dstA[1]);                       \
        gload_lds16(srcB[0] + ko, bB + dstB[0]);                       \
        if constexpr (BL == 2) gload_lds16(srcB[1] + ko, bB + dstB[1]);\
    } while (0)

    f32x4 acc[WTM][4] = {};

    STAGE(0, 0);
    STAGE(1, 1);
    STAGE(2, 2);
    // handshake for tile 0: own loads landed -> barrier -> all landed
    if constexpr (MODE == 1) asm volatile("s_waitcnt vmcnt(8)" ::: "memory");
    else                     asm volatile("s_waitcnt vmcnt(6)" ::: "memory");
    __builtin_amdgcn_s_barrier();

    int buf = 0;
    for (int t = 0; t < NK; ++t) {
        // 1. read fragments of tile t (guaranteed landed by prev handshake)
        f16x8 af[WTM], bf[4];
        #pragma unroll
        for (int i = 0; i < WTM; ++i) {
            int row = wm + i*16 + r16;
            af[i] = *(const f16x8*)&ldsA[buf][row][(g ^ ((row >> 1) & 3)) * 8];
        }
        #pragma unroll
        for (int j = 0; j < 4; ++j) {
            int row = wn + j*16 + r16;
            bf[j] = *(const f16x8*)&ldsB[buf][row][(g ^ ((row >> 1) & 3)) * 8];
        }
        // 2. my reads are complete (registers hold data)
        asm volatile("s_waitcnt lgkmcnt(0)" ::: "memory");
        __builtin_amdgcn_sched_barrier(0);
        // 3. ALL waves finished reading buf[t]
        __builtin_amdgcn_s_barrier();
        // 4. safe to overwrite buf[t%3] with tile t+3 (issue only, no wait)
        if (t + 3 < NK) STAGE(buf, t + 3);
        // 5. compute on registers; stage stream flows underneath
        __builtin_amdgcn_s_setprio(1);
        #pragma unroll
        for (int i = 0; i < WTM; ++i)
            #pragma unroll
            for (int j = 0; j < 4; ++j)
                acc[i][j] = __builtin_amdgcn_mfma_f32_16x16x32_f16(af[i], bf[j], acc[i][j], 0, 0, 0);
        __builtin_amdgcn_s_setprio(0);
        // 6. drain ONLY tile t+1's own loads (t+2, t+3 stay in flight)
        if constexpr (MODE == 1) {
            if (t + 3 < NK)      asm volatile("s_waitcnt vmcnt(8)" ::: "memory");
            else if (t + 2 < NK) asm volatile("s_waitcnt vmcnt(4)" ::: "memory");
            else if (t + 1 < NK) asm volatile("s_waitcnt vmcnt(0)" ::: "memory");
        } else {
            if (t + 3 < NK)      asm volatile("s_waitcnt vmcnt(6)" ::: "memory");
            else if (t + 2 < NK) asm volatile("s_waitcnt vmcnt(3)" ::: "memory");
            else if (t + 1 < NK) asm volatile("s_waitcnt vmcnt(0)" ::: "memory");
        }
        __builtin_amdgcn_sched_barrier(0);
        // 7. all waves' t+1 loads landed -> next iteration's reads are safe
        __builtin_amdgcn_s_barrier();
        buf = (buf == 2) ? 0 : buf + 1;
    }
    #undef STAGE

    // ---- epilogue ----
    #pragma unroll
    for (int i = 0; i < WTM; ++i) {
        #pragma unroll
        for (int j = 0; j < 4; ++j) {
            if constexpr (MODE == 0) {
                #pragma unroll
                for (int r = 0; r < 4; ++r) {
                    const int m = m0 + wm + i*16 + g*4 + r;
                    const int n = n0 + wn + j*16 + r16;
                    outF[(size_t)m*DM + n] = acc[i][j][r];
                }
            } else {
                const int n = n0 + wn + j*16 + r16;
                const int sel = n >> 10;              // 0=q 1=k 2=v (block-uniform)
                const int cc = n & 1023;
                const int h = cc >> 6, dd = cc & 63;
                if (sel == 2) {
                    const int mb = m0 + wm + i*16 + g*4;
                    const int s0 = mb & (SEQ - 1), b = mb >> 11;
                    f16x4 pk;
                    #pragma unroll
                    for (int r = 0; r < 4; ++r) pk[r] = (_Float16)acc[i][j][r];
                    *(f16x4*)(qkv + 2*BHSD + ((size_t)((b*NH + h)*HD + dd))*SEQ + s0) = pk;
                } else {
                    #pragma unroll
                    for (int r = 0; r < 4; ++r) {
                        const int m = m0 + wm + i*16 + g*4 + r;
                        float v = acc[i][j][r];
                        float vp = __shfl_xor(v, 1);          // partner column (n^1)
                        const int s = m & (SEQ - 1), b = m >> 11;
                        float2 cs = rope[(s << 5) + (dd >> 1)];
                        float o;
                        if (dd & 1) o = vp * cs.y + v * cs.x;   // x1*sin + x2*cos
                        else        o = v * cs.x - vp * cs.y;   // x1*cos - x2*sin
                        if (sel == 0) o *= 0.18033688f;         // 1/sqrt(HD) * log2(e)
                        qkv[(size_t)sel*BHSD + ((size_t)((b*NH + h)*SEQ + s))*HD + dd] = (_Float16)o;
                    }
                }
            }
        }
    }
}

// ---------------- per-KV-tile attention step (swapped QK^T, in-register softmax) ----------
__device__ __forceinline__ void process_tile(
    const _Float16 (*__restrict__ Klb)[64], const _Float16 (*__restrict__ Vlb)[64],
    const f16x8 (&qf)[2], f32x4 (&ot)[4], float &m, float &l,
    const int Rq, const int kv0, const int g, const int r16) {

    f32x4 sT[4] = {};
    const int kchunkBase = r16 & 7;
    __builtin_amdgcn_s_setprio(1);
    #pragma unroll
    for (int ks = 0; ks < 2; ++ks) {
        #pragma unroll
        for (int n = 0; n < 4; ++n) {
            f16x8 kf = *(const f16x8*)&Klb[n*16 + r16][(((ks<<2)|g) ^ kchunkBase)*8];
            sT[n] = __builtin_amdgcn_mfma_f32_16x16x32_f16(kf, qf[ks], sT[n], 0, 0, 0);
        }
    }
    __builtin_amdgcn_s_setprio(0);

    const bool full = (kv0 + 63 <= Rq);
    float sv[16];
    if (full) {
        #pragma unroll
        for (int n = 0; n < 4; ++n)
            #pragma unroll
            for (int r = 0; r < 4; ++r) sv[n*4 + r] = sT[n][r];
    } else {
        const int q = Rq + r16;
        #pragma unroll
        for (int n = 0; n < 4; ++n)
            #pragma unroll
            for (int r = 0; r < 4; ++r)
                sv[n*4 + r] = (kv0 + n*16 + 4*g + r <= q) ? sT[n][r] : -INFINITY;
    }
    float mx = sv[0];
    #pragma unroll
    for (int i = 1; i < 16; ++i) mx = fmaxf(mx, sv[i]);
    mx = red32_max(red16_max(mx));
    const bool need = (mx > m + 8.f);
    if (__any(need)) {
        float mnew = need ? mx : m;
        float al = exp2f(m - mnew);
        m = mnew;
        l *= al;
        #pragma unroll
        for (int n = 0; n < 4; ++n) ot[n] *= al;
    }
    float ps = 0.f;
    #pragma unroll
    for (int i = 0; i < 16; ++i) { sv[i] = exp2f(sv[i] - m); ps += sv[i]; }
    l += red32_add(red16_add(ps));

    uint pk[4][2];
    #pragma unroll
    for (int t = 0; t < 4; ++t)
        #pragma unroll
        for (int rp = 0; rp < 2; ++rp) {
            union { fp16x2 h; uint u; } cv;
            cv.h = __builtin_amdgcn_cvt_pkrtz(sv[t*4 + 2*rp], sv[t*4 + 2*rp + 1]);
            pk[t][rp] = cv.u;
        }
    uint w[2][4];
    #pragma unroll
    for (int kk = 0; kk < 2; ++kk)
        #pragma unroll
        for (int rp = 0; rp < 2; ++rp) {
            u32x2 s32 = __builtin_amdgcn_permlane32_swap(pk[2*kk][rp], pk[2*kk + 1][rp], false, false);
            u32x2 s16 = __builtin_amdgcn_permlane16_swap(s32[0], s32[1], false, false);
            w[kk][rp]     = s16[0];
            w[kk][2 + rp] = s16[1];
        }

    __builtin_amdgcn_s_setprio(1);
    #pragma unroll
    for (int ks = 0; ks < 2; ++ks) {
        union { uint u[4]; f16x8 h; } pb;
        #pragma unroll
        for (int j2 = 0; j2 < 4; ++j2) pb.u[j2] = w[ks][j2];
        #pragma unroll
        for (int n = 0; n < 4; ++n) {
            f16x8 vf = *(const f16x8*)&Vlb[n*16 + r16][(((ks<<2)|g) ^ kchunkBase)*8];
            ot[n] = __builtin_amdgcn_mfma_f32_16x16x32_f16(vf, pb.h, ot[n], 0, 0, 0);
        }
    }
    __builtin_amdgcn_s_setprio(0);
}

// ---------------- flash attention: diagonal-paired 64-row q-tiles, 16 q/wave ----------------
__global__ __launch_bounds__(256, 4)
void attn_kernel(const _Float16* __restrict__ qkv, _Float16* __restrict__ ao) {
    const int tid = threadIdx.x, lane = tid & 63, w = tid >> 6;
    const int g = lane >> 4, r16 = lane & 15;
    const int bh = blockIdx.x;
    const int jq = blockIdx.y;                       // 0..15
    const int q0h = (31 - jq) * 64, q0l = jq * 64;
    const _Float16* Q   = qkv + (size_t)bh * SEQ * HD;
    const _Float16* Kp  = qkv + BHSD + (size_t)bh * SEQ * HD;
    const _Float16* Vpt = qkv + 2*BHSD + (size_t)bh * SEQ * HD;   // [d][s]

    __shared__ __align__(16) _Float16 Kl[2][64][64];
    __shared__ __align__(16) _Float16 Vl[2][64][64];

    const int rA = tid >> 3,        rB = 32 + (tid >> 3);
    const int lcA = (tid & 7) ^ (rA & 7), lcB = (tid & 7) ^ (rB & 7);
    const _Float16* KsrcA = Kp  + (size_t)rA*HD + lcA*8;
    const _Float16* KsrcB = Kp  + (size_t)rB*HD + lcB*8;
    const _Float16* VsrcA = Vpt + (size_t)rA*SEQ + lcA*8;
    const _Float16* VsrcB = Vpt + (size_t)rB*SEQ + lcB*8;

    const int Rh = q0h + w*16, Rl = q0l + w*16;
    f16x8 qfh[2], qfl[2];
    #pragma unroll
    for (int ks = 0; ks < 2; ++ks) {
        qfh[ks] = *(const f16x8*)(Q + (size_t)(Rh + r16)*HD + ks*32 + g*8);
        qfl[ks] = *(const f16x8*)(Q + (size_t)(Rl + r16)*HD + ks*32 + g*8);
    }

    f32x4 oth[4] = {}, otl[4] = {};
    float mh = -INFINITY, lh = 0.f, ml_ = -INFINITY, ll_ = 0.f;

    const int nth = (q0h >> 6) + 1;
    const int ntl = (q0l >> 6) + 1;

    #define STAGE(buf, kv0) do {                                              \
        gload_lds16(KsrcA + (size_t)(kv0)*HD, &Kl[(buf)][0][0] + tid*8);      \
        gload_lds16(KsrcB + (size_t)(kv0)*HD, &Kl[(buf)][0][0] + (256+tid)*8);\
        gload_lds16(VsrcA + (kv0),            &Vl[(buf)][0][0] + tid*8);      \
        gload_lds16(VsrcB + (kv0),            &Vl[(buf)][0][0] + (256+tid)*8);\
    } while (0)

    STAGE(0, 0);
    for (int kt = 0; kt < nth; ++kt) {
        const int kv0 = kt << 6;
        __syncthreads();
        if (kt + 1 < nth) STAGE((kt + 1) & 1, (kt + 1) << 6);
        const int buf = kt & 1;

        if (kv0 <= Rh + 15)
            process_tile(Kl[buf], Vl[buf], qfh, oth, mh, lh, Rh, kv0, g, r16);
        if (kt < ntl)
            process_tile(Kl[buf], Vl[buf], qfl, otl, ml_, ll_, Rl, kv0, g, r16);
    }
    #undef STAGE

    const int b = bh >> 4, h = bh & 15;
    const float invh = 1.0f / lh, invl = 1.0f / ll_;
    _Float16* dsth = ao + ((size_t)(b*SEQ + Rh + r16))*DM + h*HD + g*4;
    _Float16* dstl = ao + ((size_t)(b*SEQ + Rl + r16))*DM + h*HD + g*4;
    #pragma unroll
    for (int n = 0; n < 4; ++n) {
        f16x4 pkh, pkl;
        #pragma unroll
        for (int r = 0; r < 4; ++r) {
            pkh[r] = (_Float16)(oth[n][r] * invh);
            pkl[r] = (_Float16)(otl[n][r] * invl);
        }
        *(f16x4*)(dsth + n*16) = pkh;
        *(f16x4*)(dstl + n*16) = pkl;
    }
}

// ---------------- launcher ----------------
extern "C" void kernel_launch(void* const* d_in, const int* in_sizes, int n_in,
                              void* d_out, int out_size, void* d_ws, size_t ws_size,
                              hipStream_t stream) {
    const float* x  = (const float*)d_in[0];
    const int*   tp = (const int*)d_in[1];
    const float* wq = (const float*)d_in[2];
    const float* wk = (const float*)d_in[3];
    const float* wv = (const float*)d_in[4];
    const float* wo = (const float*)d_in[5];
    float* out = (float*)d_out;

    char* ws = (char*)d_ws;
    _Float16* xh  = (_Float16*)(ws);                         // 16,777,216 B
    _Float16* whq = (_Float16*)(ws + 16777216);              //  6,291,456 B (wq|wk|wv)
    _Float16* woh = (_Float16*)(ws + 23068672);              //  2,097,152 B
    _Float16* qkv = (_Float16*)(ws + 25165824);              // 50,331,648 B
    _Float16* ao  = (_Float16*)(ws + 75497472);              // 16,777,216 B
    float2*   rope= (float2*)  (ws + 92274688);              //    524,288 B  (total ~92.8 MB)

    f32_to_f16<<<MROWS*DM/1024, 256, 0, stream>>>(x, xh, MROWS*DM);
    f32_to_f16<<<DM*DM/1024, 256, 0, stream>>>(wq, whq,            DM*DM);
    f32_to_f16<<<DM*DM/1024, 256, 0, stream>>>(wk, whq + DM*DM,    DM*DM);
    f32_to_f16<<<DM*DM/1024, 256, 0, stream>>>(wv, whq + 2*DM*DM,  DM*DM);
    f32_to_f16<<<DM*DM/1024, 256, 0, stream>>>(wo, woh,            DM*DM);
    rope_table<<<SEQ*32/256, 256, 0, stream>>>(tp, rope);

    gemmP<1><<<dim3(MROWS/256, 3*DM/256), 512, 0, stream>>>(xh, whq, nullptr, qkv, rope);
    attn_kernel<<<dim3(BATCH*NH, 16), 256, 0, stream>>>(qkv, ao);
    gemmP<0><<<dim3(MROWS/256, DM/128), 512, 0, stream>>>(ao, woh, out, nullptr, nullptr);
}

// Round 13
// 219.860 us; speedup vs baseline: 1.0151x; 1.0151x over previous
//
#include <hip/hip_runtime.h>
#include <hip/hip_fp16.h>

#define DM   1024
#define NH   16
#define HD   64
#define BATCH 4
#define SEQ  2048
#define MROWS (BATCH*SEQ)            // 8192
#define BHSD  ((size_t)BATCH*NH*SEQ*HD)  // 8388608 elems

using f32x4 = __attribute__((ext_vector_type(4))) float;
using f16x8 = __attribute__((ext_vector_type(8))) _Float16;
using f16x4 = __attribute__((ext_vector_type(4))) _Float16;
using fp16x2 = __attribute__((ext_vector_type(2))) __fp16;
using u32x2 = __attribute__((ext_vector_type(2))) unsigned int;

__device__ __forceinline__ void gload_lds16(const void* g, void* l) {
    __builtin_amdgcn_global_load_lds(
        (const __attribute__((address_space(1))) void*)g,
        (__attribute__((address_space(3))) void*)l, 16, 0, 0);
}

// ---- VALU-pipe cross-lane reduces via permlane*_swap builtins ----
__device__ __forceinline__ float red16_max(float v) {
    u32x2 r = __builtin_amdgcn_permlane16_swap(__float_as_uint(v), __float_as_uint(v), false, false);
    return fmaxf(__uint_as_float(r[0]), __uint_as_float(r[1]));
}
__device__ __forceinline__ float red32_max(float v) {
    u32x2 r = __builtin_amdgcn_permlane32_swap(__float_as_uint(v), __float_as_uint(v), false, false);
    return fmaxf(__uint_as_float(r[0]), __uint_as_float(r[1]));
}
__device__ __forceinline__ float red16_add(float v) {
    u32x2 r = __builtin_amdgcn_permlane16_swap(__float_as_uint(v), __float_as_uint(v), false, false);
    return __uint_as_float(r[0]) + __uint_as_float(r[1]);
}
__device__ __forceinline__ float red32_add(float v) {
    u32x2 r = __builtin_amdgcn_permlane32_swap(__float_as_uint(v), __float_as_uint(v), false, false);
    return __uint_as_float(r[0]) + __uint_as_float(r[1]);
}

// ---------------- fp32 -> fp16 cast ----------------
__global__ __launch_bounds__(256) void f32_to_f16(const float* __restrict__ in,
                                                  _Float16* __restrict__ out, int n) {
    int i = (blockIdx.x * 256 + threadIdx.x) * 4;
    if (i >= n) return;
    float4 v = *(const float4*)(in + i);
    union { _Float16 h[4]; ushort4 u; } cv;
    cv.h[0] = (_Float16)v.x; cv.h[1] = (_Float16)v.y;
    cv.h[2] = (_Float16)v.z; cv.h[3] = (_Float16)v.w;
    *(ushort4*)(out + i) = cv.u;
}

// ---------------- RoPE cos/sin table: [SEQ][32] float2 ----------------
__global__ __launch_bounds__(256) void rope_table(const int* __restrict__ pos,
                                                  float2* __restrict__ tab) {
    int idx = blockIdx.x * 256 + threadIdx.x;    // 65536
    int s = idx >> 5, j = idx & 31;
    float p = (float)pos[s];
    float invf = powf(10000.0f, -(float)j / 32.0f);
    float ang = p * invf;
    tab[idx] = make_float2(cosf(ang), sinf(ang));
}

// ---------------- phase-pipelined GEMM (m201-style, K-split halves) ----------------
// BM=256, BK=64 split into two K-half slabs (16KB A / 16|8KB B per half).
// Per K-tile: 2 phases. Phase ks: {12|8 ds_read frags (k-slice ks) -> stage ONE
// half-group of a future tile -> barrier -> lgkmcnt(0)+sched_barrier -> 32|16
// MFMA (setprio) -> barrier}. Stage schedule: P0 stages hi(t+1), P1 stages
// lo(t+2) -- progressive frees make this race-free (all waves' reads of the
// overwritten slab completed before the preceding barrier). ONE counted
// vmcnt per K-tile (ledger-verified): at P1(t) only lo(t+2) may stay in
// flight -> vmcnt(4|3); tail 4->0->skip. Loads span phases continuously.
// MODE 1 (QKV): BN=256, 8 waves 2Mx4N (wave-tile 128x64), RoPE epilogue.
// MODE 0 (WO):  BN=128, 8 waves 4Mx2N (wave-tile 64x64), fp32 out.
template<int MODE>
__global__ __launch_bounds__(512, 1)
void gemmQ(const _Float16* __restrict__ A, const _Float16* __restrict__ Bw,
           float* __restrict__ outF, _Float16* __restrict__ qkv,
           const float2* __restrict__ rope) {
    constexpr int NT  = DM / 64;                  // 16 K-tiles
    constexpr int BN  = MODE ? 256 : 128;
    constexpr int WTM = MODE ? 8 : 4;             // acc rows per wave
    __shared__ __align__(16) _Float16 ldsA[2][2][256][32];  // [buf][khalf] 64 KB
    __shared__ __align__(16) _Float16 ldsB[2][2][BN][32];   // 64 / 32 KB

    const int tid = threadIdx.x, lane = tid & 63, wid = tid >> 6;

    // XCD-aware bijective swizzle (nwg % 8 == 0 in both modes)
    const int nwg  = gridDim.x * gridDim.y;
    const int flat = blockIdx.y * gridDim.x + blockIdx.x;
    const int swz  = (flat & 7) * (nwg >> 3) + (flat >> 3);
    const int m0 = (swz % gridDim.x) * 256;
    const int n0 = (swz / gridDim.x) * BN;

    const int wm = MODE ? ((wid >> 2) * 128) : ((wid >> 1) * 64);
    const int wn = MODE ? ((wid & 3) * 64)   : ((wid & 1) * 64);
    const int g = lane >> 4, r16 = lane & 15;

    // ---- staging map: slab [256|BN][32] as 8 16B-units per 128B superrow;
    // unit u: sr=u>>3, phys p=u&7 holds logical l=p^(sr&7):
    // row = 2*sr + (l>>2), k-chunk = l&3. LDS dst linear (u*16B).
    const _Float16* sA[2]; int dA[2];
    #pragma unroll
    for (int L = 0; L < 2; ++L) {
        int u = L*512 + tid, sr = u >> 3, l = (u & 7) ^ (sr & 7);
        sA[L] = A + (size_t)(m0 + sr*2 + (l >> 2))*DM + (l & 3)*8;
        dA[L] = u*8;
    }
    const _Float16* sB[2]; int dB[2];
    #pragma unroll
    for (int L = 0; L < (MODE ? 2 : 1); ++L) {
        int u = L*512 + tid, sr = u >> 3, l = (u & 7) ^ (sr & 7);
        sB[L] = Bw + (size_t)(n0 + sr*2 + (l >> 2))*DM + (l & 3)*8;
        dB[L] = u*8;
    }

    #define STG(buf, kh, kt) do {                                           \
        const int ko = (kt)*64 + (kh)*32;                                   \
        gload_lds16(sA[0] + ko, &ldsA[buf][kh][0][0] + dA[0]);              \
        gload_lds16(sA[1] + ko, &ldsA[buf][kh][0][0] + dA[1]);              \
        gload_lds16(sB[0] + ko, &ldsB[buf][kh][0][0] + dB[0]);              \
        if constexpr (MODE == 1)                                            \
            gload_lds16(sB[1] + ko, &ldsB[buf][kh][0][0] + dB[1]);          \
    } while (0)

    // ---- per-lane read offsets (elems). row R, chunk kc ->
    // (R>>1)*64 + ((((R&1)<<2)|kc) ^ ((R>>1)&7))*8 ; keys reduce to r16-only.
    const int rhalf = r16 >> 1;
    const int tsw   = (((((r16 & 1) << 2) | g)) ^ rhalf) * 8;
    const int laneA0 = ((wm >> 1) + rhalf) * 64 + tsw;
    const int laneB0 = ((wn >> 1) + rhalf) * 64 + tsw;

    f32x4 acc[WTM][4] = {};

    // ---- prologue: lo(0), hi(0), lo(1); drain lo0+hi0 (lo1 stays in flight)
    STG(0, 0, 0);
    STG(0, 1, 0);
    STG(1, 0, 1);
    if constexpr (MODE == 1) asm volatile("s_waitcnt vmcnt(4)" ::: "memory");
    else                     asm volatile("s_waitcnt vmcnt(3)" ::: "memory");
    __builtin_amdgcn_sched_barrier(0);
    __builtin_amdgcn_s_barrier();

    #pragma unroll 2
    for (int t = 0; t < NT; ++t) {
        const int cur = t & 1;
        #pragma unroll
        for (int ks = 0; ks < 2; ++ks) {
            const _Float16* slA = &ldsA[cur][ks][0][0];
            const _Float16* slB = &ldsB[cur][ks][0][0];
            f16x8 af[WTM], bf[4];
            #pragma unroll
            for (int i = 0; i < WTM; ++i)
                af[i] = *(const f16x8*)(slA + laneA0 + i*512);
            #pragma unroll
            for (int j = 0; j < 4; ++j)
                bf[j] = *(const f16x8*)(slB + laneB0 + j*512);
            // stage one half-group of a future tile (slab freed last phase)
            if (ks == 0) { if (t + 1 < NT) STG(cur ^ 1, 1, t + 1); }   // hi(t+1)
            else         { if (t + 2 < NT) STG(cur,     0, t + 2); }   // lo(t+2)
            __builtin_amdgcn_s_barrier();
            asm volatile("s_waitcnt lgkmcnt(0)" ::: "memory");
            __builtin_amdgcn_sched_barrier(0);
            __builtin_amdgcn_s_setprio(1);
            #pragma unroll
            for (int i = 0; i < WTM; ++i)
                #pragma unroll
                for (int j = 0; j < 4; ++j)
                    acc[i][j] = __builtin_amdgcn_mfma_f32_16x16x32_f16(af[i], bf[j], acc[i][j], 0, 0, 0);
            __builtin_amdgcn_s_setprio(0);
            if (ks == 1 && t + 1 < NT) {
                // ledger: outstanding allowed = lo(t+2) only
                if (t + 2 < NT) {
                    if constexpr (MODE == 1) asm volatile("s_waitcnt vmcnt(4)" ::: "memory");
                    else                     asm volatile("s_waitcnt vmcnt(3)" ::: "memory");
                } else {
                    asm volatile("s_waitcnt vmcnt(0)" ::: "memory");
                }
                __builtin_amdgcn_sched_barrier(0);
            }
            __builtin_amdgcn_s_barrier();
        }
    }
    #undef STG

    // ---- epilogue ----
    #pragma unroll
    for (int i = 0; i < WTM; ++i) {
        #pragma unroll
        for (int j = 0; j < 4; ++j) {
            if constexpr (MODE == 0) {
                #pragma unroll
                for (int r = 0; r < 4; ++r) {
                    const int m = m0 + wm + i*16 + g*4 + r;
                    const int n = n0 + wn + j*16 + r16;
                    outF[(size_t)m*DM + n] = acc[i][j][r];
                }
            } else {
                const int n = n0 + wn + j*16 + r16;
                const int sel = n >> 10;              // 0=q 1=k 2=v (block-uniform)
                const int cc = n & 1023;
                const int h = cc >> 6, dd = cc & 63;
                if (sel == 2) {
                    const int mb = m0 + wm + i*16 + g*4;
                    const int s0 = mb & (SEQ - 1), b = mb >> 11;
                    f16x4 pk;
                    #pragma unroll
                    for (int r = 0; r < 4; ++r) pk[r] = (_Float16)acc[i][j][r];
                    *(f16x4*)(qkv + 2*BHSD + ((size_t)((b*NH + h)*HD + dd))*SEQ + s0) = pk;
                } else {
                    #pragma unroll
                    for (int r = 0; r < 4; ++r) {
                        const int m = m0 + wm + i*16 + g*4 + r;
                        float v = acc[i][j][r];
                        float vp = __shfl_xor(v, 1);          // partner column (n^1)
                        const int s = m & (SEQ - 1), b = m >> 11;
                        float2 cs = rope[(s << 5) + (dd >> 1)];
                        float o;
                        if (dd & 1) o = vp * cs.y + v * cs.x;   // x1*sin + x2*cos
                        else        o = v * cs.x - vp * cs.y;   // x1*cos - x2*sin
                        if (sel == 0) o *= 0.18033688f;         // 1/sqrt(HD) * log2(e)
                        qkv[(size_t)sel*BHSD + ((size_t)((b*NH + h)*SEQ + s))*HD + dd] = (_Float16)o;
                    }
                }
            }
        }
    }
}

// ---------------- per-KV-tile attention step (swapped QK^T, in-register softmax) ----------
__device__ __forceinline__ void process_tile(
    const _Float16 (*__restrict__ Klb)[64], const _Float16 (*__restrict__ Vlb)[64],
    const f16x8 (&qf)[2], f32x4 (&ot)[4], float &m, float &l,
    const int Rq, const int kv0, const int g, const int r16) {

    f32x4 sT[4] = {};
    const int kchunkBase = r16 & 7;
    __builtin_amdgcn_s_setprio(1);
    #pragma unroll
    for (int ks = 0; ks < 2; ++ks) {
        #pragma unroll
        for (int n = 0; n < 4; ++n) {
            f16x8 kf = *(const f16x8*)&Klb[n*16 + r16][(((ks<<2)|g) ^ kchunkBase)*8];
            sT[n] = __builtin_amdgcn_mfma_f32_16x16x32_f16(kf, qf[ks], sT[n], 0, 0, 0);
        }
    }
    __builtin_amdgcn_s_setprio(0);

    const bool full = (kv0 + 63 <= Rq);
    float sv[16];
    if (full) {
        #pragma unroll
        for (int n = 0; n < 4; ++n)
            #pragma unroll
            for (int r = 0; r < 4; ++r) sv[n*4 + r] = sT[n][r];
    } else {
        const int q = Rq + r16;
        #pragma unroll
        for (int n = 0; n < 4; ++n)
            #pragma unroll
            for (int r = 0; r < 4; ++r)
                sv[n*4 + r] = (kv0 + n*16 + 4*g + r <= q) ? sT[n][r] : -INFINITY;
    }
    float mx = sv[0];
    #pragma unroll
    for (int i = 1; i < 16; ++i) mx = fmaxf(mx, sv[i]);
    mx = red32_max(red16_max(mx));
    const bool need = (mx > m + 8.f);
    if (__any(need)) {
        float mnew = need ? mx : m;
        float al = exp2f(m - mnew);
        m = mnew;
        l *= al;
        #pragma unroll
        for (int n = 0; n < 4; ++n) ot[n] *= al;
    }
    float ps = 0.f;
    #pragma unroll
    for (int i = 0; i < 16; ++i) { sv[i] = exp2f(sv[i] - m); ps += sv[i]; }
    l += red32_add(red16_add(ps));

    uint pk[4][2];
    #pragma unroll
    for (int t = 0; t < 4; ++t)
        #pragma unroll
        for (int rp = 0; rp < 2; ++rp) {
            union { fp16x2 h; uint u; } cv;
            cv.h = __builtin_amdgcn_cvt_pkrtz(sv[t*4 + 2*rp], sv[t*4 + 2*rp + 1]);
            pk[t][rp] = cv.u;
        }
    uint w[2][4];
    #pragma unroll
    for (int kk = 0; kk < 2; ++kk)
        #pragma unroll
        for (int rp = 0; rp < 2; ++rp) {
            u32x2 s32 = __builtin_amdgcn_permlane32_swap(pk[2*kk][rp], pk[2*kk + 1][rp], false, false);
            u32x2 s16 = __builtin_amdgcn_permlane16_swap(s32[0], s32[1], false, false);
            w[kk][rp]     = s16[0];
            w[kk][2 + rp] = s16[1];
        }

    __builtin_amdgcn_s_setprio(1);
    #pragma unroll
    for (int ks = 0; ks < 2; ++ks) {
        union { uint u[4]; f16x8 h; } pb;
        #pragma unroll
        for (int j2 = 0; j2 < 4; ++j2) pb.u[j2] = w[ks][j2];
        #pragma unroll
        for (int n = 0; n < 4; ++n) {
            f16x8 vf = *(const f16x8*)&Vlb[n*16 + r16][(((ks<<2)|g) ^ kchunkBase)*8];
            ot[n] = __builtin_amdgcn_mfma_f32_16x16x32_f16(vf, pb.h, ot[n], 0, 0, 0);
        }
    }
    __builtin_amdgcn_s_setprio(0);
}

// ---------------- flash attention: diagonal-paired 64-row q-tiles, 16 q/wave ----------------
__global__ __launch_bounds__(256, 4)
void attn_kernel(const _Float16* __restrict__ qkv, _Float16* __restrict__ ao) {
    const int tid = threadIdx.x, lane = tid & 63, w = tid >> 6;
    const int g = lane >> 4, r16 = lane & 15;
    const int bh = blockIdx.x;
    const int jq = blockIdx.y;                       // 0..15
    const int q0h = (31 - jq) * 64, q0l = jq * 64;
    const _Float16* Q   = qkv + (size_t)bh * SEQ * HD;
    const _Float16* Kp  = qkv + BHSD + (size_t)bh * SEQ * HD;
    const _Float16* Vpt = qkv + 2*BHSD + (size_t)bh * SEQ * HD;   // [d][s]

    __shared__ __align__(16) _Float16 Kl[2][64][64];
    __shared__ __align__(16) _Float16 Vl[2][64][64];

    const int rA = tid >> 3,        rB = 32 + (tid >> 3);
    const int lcA = (tid & 7) ^ (rA & 7), lcB = (tid & 7) ^ (rB & 7);
    const _Float16* KsrcA = Kp  + (size_t)rA*HD + lcA*8;
    const _Float16* KsrcB = Kp  + (size_t)rB*HD + lcB*8;
    const _Float16* VsrcA = Vpt + (size_t)rA*SEQ + lcA*8;
    const _Float16* VsrcB = Vpt + (size_t)rB*SEQ + lcB*8;

    const int Rh = q0h + w*16, Rl = q0l + w*16;
    f16x8 qfh[2], qfl[2];
    #pragma unroll
    for (int ks = 0; ks < 2; ++ks) {
        qfh[ks] = *(const f16x8*)(Q + (size_t)(Rh + r16)*HD + ks*32 + g*8);
        qfl[ks] = *(const f16x8*)(Q + (size_t)(Rl + r16)*HD + ks*32 + g*8);
    }

    f32x4 oth[4] = {}, otl[4] = {};
    float mh = -INFINITY, lh = 0.f, ml_ = -INFINITY, ll_ = 0.f;

    const int nth = (q0h >> 6) + 1;
    const int ntl = (q0l >> 6) + 1;

    #define STAGE(buf, kv0) do {                                              \
        gload_lds16(KsrcA + (size_t)(kv0)*HD, &Kl[(buf)][0][0] + tid*8);      \
        gload_lds16(KsrcB + (size_t)(kv0)*HD, &Kl[(buf)][0][0] + (256+tid)*8);\
        gload_lds16(VsrcA + (kv0),            &Vl[(buf)][0][0] + tid*8);      \
        gload_lds16(VsrcB + (kv0),            &Vl[(buf)][0][0] + (256+tid)*8);\
    } while (0)

    STAGE(0, 0);
    for (int kt = 0; kt < nth; ++kt) {
        const int kv0 = kt << 6;
        __syncthreads();
        if (kt + 1 < nth) STAGE((kt + 1) & 1, (kt + 1) << 6);
        const int buf = kt & 1;

        if (kv0 <= Rh + 15)
            process_tile(Kl[buf], Vl[buf], qfh, oth, mh, lh, Rh, kv0, g, r16);
        if (kt < ntl)
            process_tile(Kl[buf], Vl[buf], qfl, otl, ml_, ll_, Rl, kv0, g, r16);
    }
    #undef STAGE

    const int b = bh >> 4, h = bh & 15;
    const float invh = 1.0f / lh, invl = 1.0f / ll_;
    _Float16* dsth = ao + ((size_t)(b*SEQ + Rh + r16))*DM + h*HD + g*4;
    _Float16* dstl = ao + ((size_t)(b*SEQ + Rl + r16))*DM + h*HD + g*4;
    #pragma unroll
    for (int n = 0; n < 4; ++n) {
        f16x4 pkh, pkl;
        #pragma unroll
        for (int r = 0; r < 4; ++r) {
            pkh[r] = (_Float16)(oth[n][r] * invh);
            pkl[r] = (_Float16)(otl[n][r] * invl);
        }
        *(f16x4*)(dsth + n*16) = pkh;
        *(f16x4*)(dstl + n*16) = pkl;
    }
}

// ---------------- launcher ----------------
extern "C" void kernel_launch(void* const* d_in, const int* in_sizes, int n_in,
                              void* d_out, int out_size, void* d_ws, size_t ws_size,
                              hipStream_t stream) {
    const float* x  = (const float*)d_in[0];
    const int*   tp = (const int*)d_in[1];
    const float* wq = (const float*)d_in[2];
    const float* wk = (const float*)d_in[3];
    const float* wv = (const float*)d_in[4];
    const float* wo = (const float*)d_in[5];
    float* out = (float*)d_out;

    char* ws = (char*)d_ws;
    _Float16* xh  = (_Float16*)(ws);                         // 16,777,216 B
    _Float16* whq = (_Float16*)(ws + 16777216);              //  6,291,456 B (wq|wk|wv)
    _Float16* woh = (_Float16*)(ws + 23068672);              //  2,097,152 B
    _Float16* qkv = (_Float16*)(ws + 25165824);              // 50,331,648 B
    _Float16* ao  = (_Float16*)(ws + 75497472);              // 16,777,216 B
    float2*   rope= (float2*)  (ws + 92274688);              //    524,288 B  (total ~92.8 MB)

    f32_to_f16<<<MROWS*DM/1024, 256, 0, stream>>>(x, xh, MROWS*DM);
    f32_to_f16<<<DM*DM/1024, 256, 0, stream>>>(wq, whq,            DM*DM);
    f32_to_f16<<<DM*DM/1024, 256, 0, stream>>>(wk, whq + DM*DM,    DM*DM);
    f32_to_f16<<<DM*DM/1024, 256, 0, stream>>>(wv, whq + 2*DM*DM,  DM*DM);
    f32_to_f16<<<DM*DM/1024, 256, 0, stream>>>(wo, woh,            DM*DM);
    rope_table<<<SEQ*32/256, 256, 0, stream>>>(tp, rope);

    gemmQ<1><<<dim3(MROWS/256, 3*DM/256), 512, 0, stream>>>(xh, whq, nullptr, qkv, rope);
    attn_kernel<<<dim3(BATCH*NH, 16), 256, 0, stream>>>(qkv, ao);
    gemmQ<0><<<dim3(MROWS/256, DM/128), 512, 0, stream>>>(ao, woh, out, nullptr, nullptr);
}

// Round 14
// 202.542 us; speedup vs baseline: 1.1018x; 1.0855x over previous
//
#include <hip/hip_runtime.h>
#include <hip/hip_fp16.h>

#define DM   1024
#define NH   16
#define HD   64
#define BATCH 4
#define SEQ  2048
#define MROWS (BATCH*SEQ)            // 8192
#define BHSD  ((size_t)BATCH*NH*SEQ*HD)  // 8388608 elems

using f32x4 = __attribute__((ext_vector_type(4))) float;
using f16x8 = __attribute__((ext_vector_type(8))) _Float16;
using f16x4 = __attribute__((ext_vector_type(4))) _Float16;
using fp16x2 = __attribute__((ext_vector_type(2))) __fp16;
using u32x2 = __attribute__((ext_vector_type(2))) unsigned int;

__device__ __forceinline__ void gload_lds16(const void* g, void* l) {
    __builtin_amdgcn_global_load_lds(
        (const __attribute__((address_space(1))) void*)g,
        (__attribute__((address_space(3))) void*)l, 16, 0, 0);
}

// ---- VALU-pipe cross-lane reduces via permlane*_swap builtins ----
__device__ __forceinline__ float red16_max(float v) {
    u32x2 r = __builtin_amdgcn_permlane16_swap(__float_as_uint(v), __float_as_uint(v), false, false);
    return fmaxf(__uint_as_float(r[0]), __uint_as_float(r[1]));
}
__device__ __forceinline__ float red32_max(float v) {
    u32x2 r = __builtin_amdgcn_permlane32_swap(__float_as_uint(v), __float_as_uint(v), false, false);
    return fmaxf(__uint_as_float(r[0]), __uint_as_float(r[1]));
}
__device__ __forceinline__ float red16_add(float v) {
    u32x2 r = __builtin_amdgcn_permlane16_swap(__float_as_uint(v), __float_as_uint(v), false, false);
    return __uint_as_float(r[0]) + __uint_as_float(r[1]);
}
__device__ __forceinline__ float red32_add(float v) {
    u32x2 r = __builtin_amdgcn_permlane32_swap(__float_as_uint(v), __float_as_uint(v), false, false);
    return __uint_as_float(r[0]) + __uint_as_float(r[1]);
}

// ---------------- fused fp32 -> fp16 cast: x + all 4 weights in ONE launch ----------------
__global__ __launch_bounds__(256) void cast_all(
    const float* __restrict__ x,  const float* __restrict__ wq,
    const float* __restrict__ wk, const float* __restrict__ wv,
    const float* __restrict__ wo, _Float16* __restrict__ xh,
    _Float16* __restrict__ whq,   _Float16* __restrict__ woh) {
    const int i = (blockIdx.x * 256 + threadIdx.x) * 4;
    const float* src; _Float16* dst; int off;
    if (i < MROWS*DM) { src = x; dst = xh; off = i; }
    else {
        int j = i - MROWS*DM;
        int sel = j >> 20;                       // DM*DM = 1048576
        off = j & (DM*DM - 1);
        src = (sel == 0) ? wq : (sel == 1) ? wk : (sel == 2) ? wv : wo;
        dst = (sel == 3) ? woh : (whq + (size_t)sel * DM * DM);
    }
    float4 v = *(const float4*)(src + off);
    union { _Float16 h[4]; ushort4 u; } cv;
    cv.h[0] = (_Float16)v.x; cv.h[1] = (_Float16)v.y;
    cv.h[2] = (_Float16)v.z; cv.h[3] = (_Float16)v.w;
    *(ushort4*)(dst + off) = cv.u;
}

// ---------------- RoPE cos/sin table: [SEQ][32] float2 ----------------
__global__ __launch_bounds__(256) void rope_table(const int* __restrict__ pos,
                                                  float2* __restrict__ tab) {
    int idx = blockIdx.x * 256 + threadIdx.x;    // 65536
    int s = idx >> 5, j = idx & 31;
    float p = (float)pos[s];
    float invf = powf(10000.0f, -(float)j / 32.0f);
    float ang = p * invf;
    tab[idx] = make_float2(cosf(ang), sinf(ang));
}

// ---------------- GEMM (R8-proven): C = A(MxK) * W^T, 128x128 tile, 2-buffer ----------------
// MODE 0: write fp32 to outF. MODE 1: fused RoPE epilogue -> q,k [B][H][S][D],
// V TRANSPOSED [B][H][D][S]; Q pre-scaled by 0.125*log2(e).
template<int MODE>
__global__ __launch_bounds__(256)
void gemm_f16(const _Float16* __restrict__ A, const _Float16* __restrict__ Bw,
              float* __restrict__ outF, _Float16* __restrict__ qkv,
              const float2* __restrict__ rope) {
    __shared__ __align__(16) _Float16 lds[2][2][128][32];   // 32 KiB
    const int tid  = threadIdx.x;
    const int lane = tid & 63;
    const int wid  = tid >> 6;
    const int m0 = blockIdx.x * 128;
    const int n0 = blockIdx.y * 128;
    const int wm = (wid >> 1) * 64;
    const int wn = (wid & 1) * 64;
    const int g   = lane >> 4;
    const int r16 = lane & 15;

    const int srow0 = (wid*2 + 0)*16 + (lane >> 2);
    const int srow1 = (wid*2 + 1)*16 + (lane >> 2);
    const int sch0 = (lane & 3) ^ ((srow0 >> 1) & 3);
    const int sch1 = (lane & 3) ^ ((srow1 >> 1) & 3);
    const _Float16* Asrc0 = A  + (size_t)(m0 + srow0)*DM + sch0*8;
    const _Float16* Asrc1 = A  + (size_t)(m0 + srow1)*DM + sch1*8;
    const _Float16* Bsrc0 = Bw + (size_t)(n0 + srow0)*DM + sch0*8;
    const _Float16* Bsrc1 = Bw + (size_t)(n0 + srow1)*DM + sch1*8;

    f32x4 acc[4][4] = {};

    #define STAGE(buf, kt) do {                                           \
        const int koff = (kt)*32;                                         \
        _Float16* bA = &lds[(buf)][0][0][0];                              \
        _Float16* bB = &lds[(buf)][1][0][0];                              \
        gload_lds16(Asrc0 + koff, bA + (wid*2 + 0)*512);                  \
        gload_lds16(Asrc1 + koff, bA + (wid*2 + 1)*512);                  \
        gload_lds16(Bsrc0 + koff, bB + (wid*2 + 0)*512);                  \
        gload_lds16(Bsrc1 + koff, bB + (wid*2 + 1)*512);                  \
    } while (0)

    STAGE(0, 0);
    for (int kt = 0; kt < 32; ++kt) {
        __syncthreads();
        if (kt + 1 < 32) STAGE((kt + 1) & 1, kt + 1);
        const int buf = kt & 1;
        f16x8 af[4], bf[4];
        #pragma unroll
        for (int i = 0; i < 4; ++i) {
            int rowa = wm + i*16 + r16;
            af[i] = *(const f16x8*)&lds[buf][0][rowa][(g ^ ((rowa >> 1) & 3)) * 8];
            int rowb = wn + i*16 + r16;
            bf[i] = *(const f16x8*)&lds[buf][1][rowb][(g ^ ((rowb >> 1) & 3)) * 8];
        }
        __builtin_amdgcn_s_setprio(1);
        #pragma unroll
        for (int i = 0; i < 4; ++i)
            #pragma unroll
            for (int j = 0; j < 4; ++j)
                acc[i][j] = __builtin_amdgcn_mfma_f32_16x16x32_f16(af[i], bf[j], acc[i][j], 0, 0, 0);
        __builtin_amdgcn_s_setprio(0);
    }
    #undef STAGE

    // epilogue
    #pragma unroll
    for (int i = 0; i < 4; ++i) {
        #pragma unroll
        for (int j = 0; j < 4; ++j) {
            if constexpr (MODE == 0) {
                #pragma unroll
                for (int r = 0; r < 4; ++r) {
                    const int m = m0 + wm + i*16 + g*4 + r;
                    const int n = n0 + wn + j*16 + r16;
                    outF[(size_t)m*DM + n] = acc[i][j][r];
                }
            } else {
                const int n = n0 + wn + j*16 + r16;
                const int sel = n >> 10;              // 0=q 1=k 2=v (block-uniform)
                const int cc = n & 1023;
                const int h = cc >> 6, dd = cc & 63;
                if (sel == 2) {
                    const int mb = m0 + wm + i*16 + g*4;
                    const int s0 = mb & (SEQ - 1), b = mb >> 11;
                    f16x4 pk;
                    #pragma unroll
                    for (int r = 0; r < 4; ++r) pk[r] = (_Float16)acc[i][j][r];
                    *(f16x4*)(qkv + 2*BHSD + ((size_t)((b*NH + h)*HD + dd))*SEQ + s0) = pk;
                } else {
                    #pragma unroll
                    for (int r = 0; r < 4; ++r) {
                        const int m = m0 + wm + i*16 + g*4 + r;
                        float v = acc[i][j][r];
                        float vp = __shfl_xor(v, 1);          // partner column (n^1)
                        const int s = m & (SEQ - 1), b = m >> 11;
                        float2 cs = rope[(s << 5) + (dd >> 1)];
                        float o;
                        if (dd & 1) o = vp * cs.y + v * cs.x;   // x1*sin + x2*cos
                        else        o = v * cs.x - vp * cs.y;   // x1*cos - x2*sin
                        if (sel == 0) o *= 0.18033688f;         // 1/sqrt(HD) * log2(e)
                        qkv[(size_t)sel*BHSD + ((size_t)((b*NH + h)*SEQ + s))*HD + dd] = (_Float16)o;
                    }
                }
            }
        }
    }
}

// ---------------- softmax for one q-tile's S^T fragments -> PV B-frag words ----------------
__device__ __forceinline__ void softmax_frag(
    const f32x4 (&sT)[4], f32x4 (&ot)[4], float &m, float &l,
    const int Rq, const int kv0, const int g, const int r16, uint (&w)[2][4]) {

    const bool full = (kv0 + 63 <= Rq);          // wave-uniform
    float sv[16];
    if (full) {
        #pragma unroll
        for (int n = 0; n < 4; ++n)
            #pragma unroll
            for (int r = 0; r < 4; ++r) sv[n*4 + r] = sT[n][r];
    } else {
        const int q = Rq + r16;
        #pragma unroll
        for (int n = 0; n < 4; ++n)
            #pragma unroll
            for (int r = 0; r < 4; ++r)
                sv[n*4 + r] = (kv0 + n*16 + 4*g + r <= q) ? sT[n][r] : -INFINITY;
    }
    float mx = sv[0];
    #pragma unroll
    for (int i = 1; i < 16; ++i) mx = fmaxf(mx, sv[i]);
    mx = red32_max(red16_max(mx));
    // defer-max (T13): rescale only when max grew by > 8 (log2 units -> P <= 256)
    const bool need = (mx > m + 8.f);
    if (__any(need)) {
        float mnew = need ? mx : m;
        float al = exp2f(m - mnew);
        m = mnew;
        l *= al;
        #pragma unroll
        for (int n = 0; n < 4; ++n) ot[n] *= al;
    }
    float ps = 0.f;
    #pragma unroll
    for (int i = 0; i < 16; ++i) { sv[i] = exp2f(sv[i] - m); ps += sv[i]; }
    l += red32_add(red16_add(ps));

    // pack to fp16 pairs then permlane-swap into PV B-frag layout
    uint pk[4][2];
    #pragma unroll
    for (int t = 0; t < 4; ++t)
        #pragma unroll
        for (int rp = 0; rp < 2; ++rp) {
            union { fp16x2 h; uint u; } cv;
            cv.h = __builtin_amdgcn_cvt_pkrtz(sv[t*4 + 2*rp], sv[t*4 + 2*rp + 1]);
            pk[t][rp] = cv.u;
        }
    #pragma unroll
    for (int kk = 0; kk < 2; ++kk)
        #pragma unroll
        for (int rp = 0; rp < 2; ++rp) {
            u32x2 s32 = __builtin_amdgcn_permlane32_swap(pk[2*kk][rp], pk[2*kk + 1][rp], false, false);
            u32x2 s16 = __builtin_amdgcn_permlane16_swap(s32[0], s32[1], false, false);
            w[kk][rp]     = s16[0];
            w[kk][2 + rp] = s16[1];
        }
}

// ---------------- merged per-KV-tile step: ONE set of K/V fragment reads feeds BOTH ----------
// hi and lo q-tiles (halves ds_read_b128 per MFMA -- attn's binding pipe).
__device__ __forceinline__ void process_tile2(
    const _Float16 (*__restrict__ Klb)[64], const _Float16 (*__restrict__ Vlb)[64],
    const f16x8 (&qfh)[2], const f16x8 (&qfl)[2],
    f32x4 (&oth)[4], f32x4 (&otl)[4],
    float &mh, float &lh, float &ml, float &ll,
    const int Rh, const int Rl, const bool doLo,
    const int kv0, const int g, const int r16) {

    const int kchunkBase = r16 & 7;

    // ---- S^T = K Q^T for both q-tiles off one kf load ----
    f32x4 sTh[4] = {}, sTl[4] = {};
    __builtin_amdgcn_s_setprio(1);
    #pragma unroll
    for (int ks = 0; ks < 2; ++ks) {
        f16x8 kf[4];
        #pragma unroll
        for (int n = 0; n < 4; ++n)
            kf[n] = *(const f16x8*)&Klb[n*16 + r16][(((ks<<2)|g) ^ kchunkBase)*8];
        #pragma unroll
        for (int n = 0; n < 4; ++n)
            sTh[n] = __builtin_amdgcn_mfma_f32_16x16x32_f16(kf[n], qfh[ks], sTh[n], 0, 0, 0);
        if (doLo) {
            #pragma unroll
            for (int n = 0; n < 4; ++n)
                sTl[n] = __builtin_amdgcn_mfma_f32_16x16x32_f16(kf[n], qfl[ks], sTl[n], 0, 0, 0);
        }
    }
    __builtin_amdgcn_s_setprio(0);

    // ---- softmax (in-register, log2 domain) ----
    uint wh[2][4], wl[2][4];
    softmax_frag(sTh, oth, mh, lh, Rh, kv0, g, r16, wh);
    if (doLo) softmax_frag(sTl, otl, ml, ll, Rl, kv0, g, r16, wl);

    // ---- O^T += V^T P^T for both q-tiles off one vf load ----
    __builtin_amdgcn_s_setprio(1);
    #pragma unroll
    for (int ks = 0; ks < 2; ++ks) {
        f16x8 vf[4];
        #pragma unroll
        for (int n = 0; n < 4; ++n)
            vf[n] = *(const f16x8*)&Vlb[n*16 + r16][(((ks<<2)|g) ^ kchunkBase)*8];
        union { uint u[4]; f16x8 h; } pbh;
        #pragma unroll
        for (int j2 = 0; j2 < 4; ++j2) pbh.u[j2] = wh[ks][j2];
        #pragma unroll
        for (int n = 0; n < 4; ++n)
            oth[n] = __builtin_amdgcn_mfma_f32_16x16x32_f16(vf[n], pbh.h, oth[n], 0, 0, 0);
        if (doLo) {
            union { uint u[4]; f16x8 h; } pbl;
            #pragma unroll
            for (int j2 = 0; j2 < 4; ++j2) pbl.u[j2] = wl[ks][j2];
            #pragma unroll
            for (int n = 0; n < 4; ++n)
                otl[n] = __builtin_amdgcn_mfma_f32_16x16x32_f16(vf[n], pbl.h, otl[n], 0, 0, 0);
        }
    }
    __builtin_amdgcn_s_setprio(0);
}

// ---------------- flash attention: diagonal-paired 64-row q-tiles, 16 q/wave ----------------
__global__ __launch_bounds__(256, 4)
void attn_kernel(const _Float16* __restrict__ qkv, _Float16* __restrict__ ao) {
    const int tid = threadIdx.x, lane = tid & 63, w = tid >> 6;
    const int g = lane >> 4, r16 = lane & 15;
    const int bh = blockIdx.x;
    const int jq = blockIdx.y;                       // 0..15
    const int q0h = (31 - jq) * 64, q0l = jq * 64;
    const _Float16* Q   = qkv + (size_t)bh * SEQ * HD;
    const _Float16* Kp  = qkv + BHSD + (size_t)bh * SEQ * HD;
    const _Float16* Vpt = qkv + 2*BHSD + (size_t)bh * SEQ * HD;   // [d][s]

    __shared__ __align__(16) _Float16 Kl[2][64][64];
    __shared__ __align__(16) _Float16 Vl[2][64][64];

    const int rA = tid >> 3,        rB = 32 + (tid >> 3);
    const int lcA = (tid & 7) ^ (rA & 7), lcB = (tid & 7) ^ (rB & 7);
    const _Float16* KsrcA = Kp  + (size_t)rA*HD + lcA*8;
    const _Float16* KsrcB = Kp  + (size_t)rB*HD + lcB*8;
    const _Float16* VsrcA = Vpt + (size_t)rA*SEQ + lcA*8;
    const _Float16* VsrcB = Vpt + (size_t)rB*SEQ + lcB*8;

    const int Rh = q0h + w*16, Rl = q0l + w*16;
    f16x8 qfh[2], qfl[2];
    #pragma unroll
    for (int ks = 0; ks < 2; ++ks) {
        qfh[ks] = *(const f16x8*)(Q + (size_t)(Rh + r16)*HD + ks*32 + g*8);
        qfl[ks] = *(const f16x8*)(Q + (size_t)(Rl + r16)*HD + ks*32 + g*8);
    }

    f32x4 oth[4] = {}, otl[4] = {};
    float mh = -INFINITY, lh = 0.f, ml_ = -INFINITY, ll_ = 0.f;

    const int nth = (q0h >> 6) + 1;                  // staged tiles (covers hi q-tile)
    const int ntl = (q0l >> 6) + 1;                  // lo-compute tiles

    #define STAGE(buf, kv0) do {                                              \
        gload_lds16(KsrcA + (size_t)(kv0)*HD, &Kl[(buf)][0][0] + tid*8);      \
        gload_lds16(KsrcB + (size_t)(kv0)*HD, &Kl[(buf)][0][0] + (256+tid)*8);\
        gload_lds16(VsrcA + (kv0),            &Vl[(buf)][0][0] + tid*8);      \
        gload_lds16(VsrcB + (kv0),            &Vl[(buf)][0][0] + (256+tid)*8);\
    } while (0)

    STAGE(0, 0);
    for (int kt = 0; kt < nth; ++kt) {
        const int kv0 = kt << 6;
        __syncthreads();
        if (kt + 1 < nth) STAGE((kt + 1) & 1, (kt + 1) << 6);
        const int buf = kt & 1;

        process_tile2(Kl[buf], Vl[buf], qfh, qfl, oth, otl,
                      mh, lh, ml_, ll_, Rh, Rl, (kt < ntl), kv0, g, r16);
    }
    #undef STAGE

    const int b = bh >> 4, h = bh & 15;
    const float invh = 1.0f / lh, invl = 1.0f / ll_;
    _Float16* dsth = ao + ((size_t)(b*SEQ + Rh + r16))*DM + h*HD + g*4;
    _Float16* dstl = ao + ((size_t)(b*SEQ + Rl + r16))*DM + h*HD + g*4;
    #pragma unroll
    for (int n = 0; n < 4; ++n) {
        f16x4 pkh, pkl;
        #pragma unroll
        for (int r = 0; r < 4; ++r) {
            pkh[r] = (_Float16)(oth[n][r] * invh);
            pkl[r] = (_Float16)(otl[n][r] * invl);
        }
        *(f16x4*)(dsth + n*16) = pkh;
        *(f16x4*)(dstl + n*16) = pkl;
    }
}

// ---------------- launcher ----------------
extern "C" void kernel_launch(void* const* d_in, const int* in_sizes, int n_in,
                              void* d_out, int out_size, void* d_ws, size_t ws_size,
                              hipStream_t stream) {
    const float* x  = (const float*)d_in[0];
    const int*   tp = (const int*)d_in[1];
    const float* wq = (const float*)d_in[2];
    const float* wk = (const float*)d_in[3];
    const float* wv = (const float*)d_in[4];
    const float* wo = (const float*)d_in[5];
    float* out = (float*)d_out;

    char* ws = (char*)d_ws;
    _Float16* xh  = (_Float16*)(ws);                         // 16,777,216 B
    _Float16* whq = (_Float16*)(ws + 16777216);              //  6,291,456 B (wq|wk|wv)
    _Float16* woh = (_Float16*)(ws + 23068672);              //  2,097,152 B
    _Float16* qkv = (_Float16*)(ws + 25165824);              // 50,331,648 B
    _Float16* ao  = (_Float16*)(ws + 75497472);              // 16,777,216 B
    float2*   rope= (float2*)  (ws + 92274688);              //    524,288 B  (total ~92.8 MB)

    cast_all<<<(MROWS*DM + 4*DM*DM)/1024, 256, 0, stream>>>(x, wq, wk, wv, wo, xh, whq, woh);
    rope_table<<<SEQ*32/256, 256, 0, stream>>>(tp, rope);

    gemm_f16<1><<<dim3(MROWS/128, 3*DM/128), 256, 0, stream>>>(xh, whq, nullptr, qkv, rope);
    attn_kernel<<<dim3(BATCH*NH, 16), 256, 0, stream>>>(qkv, ao);
    gemm_f16<0><<<dim3(MROWS/128, DM/128), 256, 0, stream>>>(ao, woh, out, nullptr, nullptr);
}